// Round 13
// baseline (140.360 us; speedup 1.0000x reference)
//
#include <hip/hip_runtime.h>

#define N_NODES 50000
#define N_EDGES 800000
#define DIM 128
#define NB 391          // buckets of 128 dst nodes
#define CAP 2560        // padded capacity per bucket
#define NCH 7           // src chunks (kept for csr chunk-sort)
#define BIN_CHUNK 4096
#define BIN_BLOCKS 196
#define GEMM_TILES 782   // ceil(50000/64)
#define AGG_TILES 782    // 64 nodes per block per panel
#define NPANEL 4

typedef unsigned int uint;
typedef unsigned short ushort;
typedef __attribute__((ext_vector_type(8))) __bf16 bf16x8;
typedef __attribute__((ext_vector_type(4))) float f32x4;

__device__ __forceinline__ uint f2bf(float f) {
    uint u = __float_as_uint(f);
    return (u + 0x7FFFu + ((u >> 16) & 1u)) >> 16;
}
__device__ __forceinline__ float2 bf2f2(uint u) {
    return make_float2(__uint_as_float(u << 16), __uint_as_float(u & 0xFFFF0000u));
}

// ---------------- prep: W^T bf16 pre-pack + bucket cursor init ----------------

__global__ __launch_bounds__(256) void prep_kernel(const float* __restrict__ W1,
                                                   const float* __restrict__ W2,
                                                   uint* __restrict__ Wt1,
                                                   uint* __restrict__ Wt2,
                                                   int* __restrict__ bincursor) {
    int idx = blockIdx.x * 256 + threadIdx.x;
    if (idx < 16384) {
        const float* W = (idx < 8192) ? W1 : W2;
        uint* Wt = (idx < 8192) ? Wt1 : Wt2;
        int i = idx & 8191;
        int n = i >> 6, k2 = i & 63;
        Wt[i] = f2bf(W[(2 * k2) * DIM + n]) | (f2bf(W[(2 * k2 + 1) * DIM + n]) << 16);
    } else {
        int b = idx - 16384;
        if (b < NB) bincursor[b] = b * CAP;
    }
}

// ---------------- panel write helper: H[panel][row][32 cols bf16] ----------------
// ushort index = (panel*N_NODES + row)*32 + (within-panel col)

// ---------------- gemm1: 64-row tile from global fp32 -> unscaled bf16 panels ----------------

__device__ __forceinline__ void gemm_tile64(const float* __restrict__ X,
                                            const uint* __restrict__ Wt, int base,
                                            uint* __restrict__ HP) {
    int t = threadIdx.x;
    int wv = t >> 6;
    int l = t & 63;
    int col = l & 15;
    int g = l >> 4;
    int grow = base + wv * 16 + col;
    int ar = grow > N_NODES - 1 ? N_NODES - 1 : grow;

    bf16x8 af[4];
    const float4* Xr = (const float4*)(X + (size_t)ar * DIM);
#pragma unroll
    for (int kk = 0; kk < 4; ++kk) {
        float4 x0 = Xr[kk * 8 + g * 2];
        float4 x1 = Xr[kk * 8 + g * 2 + 1];
        uint4 p;
        p.x = f2bf(x0.x) | (f2bf(x0.y) << 16);
        p.y = f2bf(x0.z) | (f2bf(x0.w) << 16);
        p.z = f2bf(x1.x) | (f2bf(x1.y) << 16);
        p.w = f2bf(x1.z) | (f2bf(x1.w) << 16);
        af[kk] = __builtin_bit_cast(bf16x8, p);
    }

    const uint4* Wr = (const uint4*)Wt;
    f32x4 acc[8];
#pragma unroll
    for (int n = 0; n < 8; ++n) acc[n] = (f32x4){0.f, 0.f, 0.f, 0.f};

#pragma unroll
    for (int n = 0; n < 8; ++n) {
        const uint4* wrow = Wr + (size_t)(n * 16 + col) * 16;
#pragma unroll
        for (int kk = 0; kk < 4; ++kk) {
            bf16x8 bf = __builtin_bit_cast(bf16x8, wrow[kk * 4 + g]);
            acc[n] = __builtin_amdgcn_mfma_f32_16x16x32_bf16(af[kk], bf, acc[n], 0, 0, 0);
        }
    }

    ushort* Hp = (ushort*)HP;
#pragma unroll
    for (int j = 0; j < 4; ++j) {
        int row = base + wv * 16 + g * 4 + j;
        if (row < N_NODES) {
#pragma unroll
            for (int n = 0; n < 8; ++n) {
                Hp[((size_t)((n >> 1) * N_NODES + row)) * 32 + (n & 1) * 16 + col] =
                    (ushort)f2bf(acc[n][j]);
            }
        }
    }
}

// ---------------- K2: bin (blocks<196) || gemm1 (rest) ----------------

__global__ __launch_bounds__(256) void bin_gemm1_kernel(const int* __restrict__ ei,
                                                        int* __restrict__ bincursor,
                                                        uint* __restrict__ pairs,
                                                        const float* __restrict__ x,
                                                        const uint* __restrict__ Wt1,
                                                        uint* __restrict__ HP) {
    if (blockIdx.x >= BIN_BLOCKS) {
        gemm_tile64(x, Wt1, (blockIdx.x - BIN_BLOCKS) * 64, HP);
        return;
    }
    __shared__ int lh[NB];
    __shared__ int lbase[NB];
    int t = threadIdx.x;
    int eb = blockIdx.x * BIN_CHUNK;

    for (int b = t; b < NB; b += 256) lh[b] = 0;
    __syncthreads();

    int s_reg[16], d_reg[16];
#pragma unroll
    for (int i = 0; i < 16; ++i) {
        int e = eb + i * 256 + t;
        if (e < N_EDGES) {
            s_reg[i] = ei[e];
            d_reg[i] = ei[N_EDGES + e];
            atomicAdd(&lh[d_reg[i] >> 7], 1);
        } else {
            d_reg[i] = -1;
        }
    }
    __syncthreads();

    for (int b = t; b < NB; b += 256) {
        int c = lh[b];
        lbase[b] = c ? atomicAdd(&bincursor[b], c) : 0;
    }
    __syncthreads();
    for (int b = t; b < NB; b += 256) lh[b] = 0;
    __syncthreads();

#pragma unroll
    for (int i = 0; i < 16; ++i) {
        int d = d_reg[i];
        if (d >= 0) {
            int bin = d >> 7;
            int r = atomicAdd(&lh[bin], 1);
            pairs[lbase[bin] + r] = ((uint)s_reg[i] << 7) | (uint)(d & 127);
        }
    }
}

// ---------------- fill2: per-bucket CSR build, chunk-sorted per node ----------------

__global__ __launch_bounds__(256) void fill2_kernel(const uint* __restrict__ pairs,
                                                    const int* __restrict__ bincursor,
                                                    int* __restrict__ rowbeg,
                                                    int* __restrict__ rowend,
                                                    float* __restrict__ dinv,
                                                    int* __restrict__ csr_src) {
    __shared__ int cnt[128 * 8];
    __shared__ int nsum[128];
    __shared__ int nbase[128];
    int t = threadIdx.x;
    int blk = blockIdx.x;
    int bs = blk * CAP;
    int be = bincursor[blk];

    for (int i = t; i < 128 * 8; i += 256) cnt[i] = 0;
    __syncthreads();

    for (int p = bs + t; p < be; p += 256) {
        uint pr = pairs[p];
        atomicAdd(&cnt[(pr & 127u) * 8 + (pr >> 20)], 1);
    }
    __syncthreads();

    if (t < 128) {
        int s = 0;
#pragma unroll
        for (int c = 0; c < NCH; ++c) s += cnt[t * 8 + c];
        nsum[t] = s;
        nbase[t] = s;
    }
    __syncthreads();
#pragma unroll
    for (int off = 1; off < 128; off <<= 1) {
        int v = (t < 128 && t >= off) ? nbase[t - off] : 0;
        __syncthreads();
        if (t < 128) nbase[t] += v;
        __syncthreads();
    }

    if (t < 128) {
        int ex = nbase[t] - nsum[t];
        int node = blk * 128 + t;
        if (node < N_NODES) {
            rowbeg[node] = bs + ex;
            rowend[node] = bs + nbase[t];
            dinv[node] = rsqrtf((float)nsum[t] + 1.0f);
        }
        int run = ex;
#pragma unroll
        for (int c = 0; c < NCH; ++c) {
            int v = cnt[t * 8 + c];
            cnt[t * 8 + c] = run;
            run += v;
        }
    }
    __syncthreads();

    for (int p = bs + t; p < be; p += 256) {
        uint pr = pairs[p];
        int r = atomicAdd(&cnt[(pr & 127u) * 8 + (pr >> 20)], 1);
        csr_src[bs + r] = (int)(pr >> 7);
    }
}

// ---------------- aggP: panel-phased gather ----------------
// panel = blockIdx & 3 (XCD-affine under round-robin blockIdx->XCD); tile = blockIdx >> 2.
// 4 lanes/node (li = lane&3 reads uint4 = 8 cols), 16 nodes/wave, 8-deep MLP.

template <bool DSRC, bool OBF>
__global__ __launch_bounds__(256) void aggP_kernel(const int* __restrict__ rowbeg,
                                                   const int* __restrict__ rowend,
                                                   const int* __restrict__ csr_src,
                                                   const uint* __restrict__ HP,
                                                   const float* __restrict__ dinv,
                                                   const float* __restrict__ bias,
                                                   const float* __restrict__ resid,
                                                   void* __restrict__ outv) {
    int bid = blockIdx.x;
    int panel = bid & 3;
    int tile = bid >> 2;
    int t = threadIdx.x;
    int wv = t >> 6;
    int l = t & 63;
    int sub = l >> 2;
    int li = l & 3;
    int node = tile * 64 + wv * 16 + sub;
    bool valid = node < N_NODES;
    int nn = valid ? node : N_NODES - 1;

    int beg = rowbeg[nn];
    int end = valid ? rowend[nn] : beg;
    float di = dinv[nn];

    const uint4* H = (const uint4*)HP + (size_t)panel * (N_NODES * 4);

    float a0, a1, a2, a3, a4, a5, a6, a7;
    {
        uint4 su = H[(size_t)nn * 4 + li];
        float2 v0 = bf2f2(su.x), v1 = bf2f2(su.y), v2 = bf2f2(su.z), v3 = bf2f2(su.w);
        float sf = DSRC ? di : 1.0f;
        a0 = sf * v0.x; a1 = sf * v0.y; a2 = sf * v1.x; a3 = sf * v1.y;
        a4 = sf * v2.x; a5 = sf * v2.y; a6 = sf * v3.x; a7 = sf * v3.y;
    }

#define ADDF8(u, f)                                                               \
    {                                                                             \
        float2 v0 = bf2f2(u.x), v1 = bf2f2(u.y), v2 = bf2f2(u.z), v3 = bf2f2(u.w);\
        a0 += f * v0.x; a1 += f * v0.y; a2 += f * v1.x; a3 += f * v1.y;           \
        a4 += f * v2.x; a5 += f * v2.y; a6 += f * v3.x; a7 += f * v3.y;           \
    }

    int e = beg;
    for (; e + 7 < end; e += 8) {
        int s[8];
#pragma unroll
        for (int i = 0; i < 8; ++i) s[i] = csr_src[e + i];
        uint4 u[8];
#pragma unroll
        for (int i = 0; i < 8; ++i) u[i] = H[(size_t)s[i] * 4 + li];
        float f[8];
#pragma unroll
        for (int i = 0; i < 8; ++i) f[i] = DSRC ? dinv[s[i]] : 1.0f;
#pragma unroll
        for (int i = 0; i < 8; ++i) ADDF8(u[i], f[i]);
    }
    if (e + 3 < end) {
        int s[4];
#pragma unroll
        for (int i = 0; i < 4; ++i) s[i] = csr_src[e + i];
        uint4 u[4];
#pragma unroll
        for (int i = 0; i < 4; ++i) u[i] = H[(size_t)s[i] * 4 + li];
        float f[4];
#pragma unroll
        for (int i = 0; i < 4; ++i) f[i] = DSRC ? dinv[s[i]] : 1.0f;
#pragma unroll
        for (int i = 0; i < 4; ++i) ADDF8(u[i], f[i]);
        e += 4;
    }
    for (; e < end; ++e) {
        int s = csr_src[e];
        uint4 u = H[(size_t)s * 4 + li];
        float f = DSRC ? dinv[s] : 1.0f;
        ADDF8(u, f);
    }
#undef ADDF8

    if (!valid) return;

    const float4* B4 = (const float4*)(bias + panel * 32 + li * 8);
    float4 bb0 = B4[0], bb1 = B4[1];
    float r0 = a0 * di + bb0.x, r1 = a1 * di + bb0.y;
    float r2 = a2 * di + bb0.z, r3 = a3 * di + bb0.w;
    float r4 = a4 * di + bb1.x, r5 = a5 * di + bb1.y;
    float r6 = a6 * di + bb1.z, r7 = a7 * di + bb1.w;

    if (OBF) {
        uint4 o;
        o.x = f2bf(fmaxf(r0, 0.f)) | (f2bf(fmaxf(r1, 0.f)) << 16);
        o.y = f2bf(fmaxf(r2, 0.f)) | (f2bf(fmaxf(r3, 0.f)) << 16);
        o.z = f2bf(fmaxf(r4, 0.f)) | (f2bf(fmaxf(r5, 0.f)) << 16);
        o.w = f2bf(fmaxf(r6, 0.f)) | (f2bf(fmaxf(r7, 0.f)) << 16);
        ((uint4*)outv)[(size_t)(panel * N_NODES + node) * 4 + li] = o;
    } else {
        const float4* R4 = (const float4*)(resid + (size_t)node * DIM + panel * 32 + li * 8);
        float4 x0 = R4[0], x1 = R4[1];
        r0 += x0.x; r1 += x0.y; r2 += x0.z; r3 += x0.w;
        r4 += x1.x; r5 += x1.y; r6 += x1.z; r7 += x1.w;
        float4* O4 = (float4*)((float*)outv + (size_t)node * DIM + panel * 32 + li * 8);
        O4[0] = make_float4(fmaxf(r0, 0.f), fmaxf(r1, 0.f), fmaxf(r2, 0.f), fmaxf(r3, 0.f));
        O4[1] = make_float4(fmaxf(r4, 0.f), fmaxf(r5, 0.f), fmaxf(r6, 0.f), fmaxf(r7, 0.f));
    }
}

// ---------------- gemm2: 64-row tile, A from out1 panels (bf16), dinv-scaled panel out ----------------

__global__ __launch_bounds__(256) void gemm2_kernel(const uint* __restrict__ out1P,
                                                    const uint* __restrict__ Wt,
                                                    const float* __restrict__ dinv,
                                                    uint* __restrict__ HP) {
    int t = threadIdx.x;
    int wv = t >> 6;
    int l = t & 63;
    int col = l & 15;
    int g = l >> 4;
    int base = blockIdx.x * 64;
    int grow = base + wv * 16 + col;
    int ar = grow > N_NODES - 1 ? N_NODES - 1 : grow;

    bf16x8 af[4];
#pragma unroll
    for (int kk = 0; kk < 4; ++kk) {
        af[kk] = __builtin_bit_cast(
            bf16x8, *(const uint4*)(out1P + ((size_t)(kk * N_NODES + ar)) * 16 + g * 4));
    }

    const uint4* Wr = (const uint4*)Wt;
    f32x4 acc[8];
#pragma unroll
    for (int n = 0; n < 8; ++n) acc[n] = (f32x4){0.f, 0.f, 0.f, 0.f};

#pragma unroll
    for (int n = 0; n < 8; ++n) {
        const uint4* wrow = Wr + (size_t)(n * 16 + col) * 16;
#pragma unroll
        for (int kk = 0; kk < 4; ++kk) {
            bf16x8 bf = __builtin_bit_cast(bf16x8, wrow[kk * 4 + g]);
            acc[n] = __builtin_amdgcn_mfma_f32_16x16x32_bf16(af[kk], bf, acc[n], 0, 0, 0);
        }
    }

    ushort* Hp = (ushort*)HP;
#pragma unroll
    for (int j = 0; j < 4; ++j) {
        int row = base + wv * 16 + g * 4 + j;
        if (row < N_NODES) {
            float di = dinv[row];
#pragma unroll
            for (int n = 0; n < 8; ++n) {
                Hp[((size_t)((n >> 1) * N_NODES + row)) * 32 + (n & 1) * 16 + col] =
                    (ushort)f2bf(acc[n][j] * di);
            }
        }
    }
}

// ---------------- launch ----------------

extern "C" void kernel_launch(void* const* d_in, const int* in_sizes, int n_in,
                              void* d_out, int out_size, void* d_ws, size_t ws_size,
                              hipStream_t stream) {
    const float* x = (const float*)d_in[0];
    const int* edge_index = (const int*)d_in[1];
    const float* W1 = (const float*)d_in[2];
    const float* b1 = (const float*)d_in[3];
    const float* W2 = (const float*)d_in[4];
    const float* b2 = (const float*)d_in[5];
    float* out = (float*)d_out;

    char* ws = (char*)d_ws;
    int*   bincursor = (int*)(ws + 0);              // 1.6 KB
    float* dinv      = (float*)(ws + (64 << 10));   // 200 KB
    int*   rowbeg    = (int*)(ws + (320 << 10));    // 200 KB
    int*   rowend    = (int*)(ws + (576 << 10));    // 200 KB
    int*   csr_src   = (int*)(ws + (1 << 20));      // 4.0 MB (padded)
    uint*  pairs     = (uint*)(ws + (6 << 20));     // 4.0 MB (packed, padded)
    uint*  HsP       = (uint*)(ws + (11 << 20));    // 12.8 MB bf16 panels (conv1 h, then conv2 h)
    uint*  out1P     = (uint*)(ws + (24 << 20));    // 12.8 MB bf16 panels (relu out1)
    uint*  Wt1       = (uint*)(ws + (37 << 20));    // 32 KB
    uint*  Wt2       = (uint*)(ws + (37 << 20) + (64 << 10));  // 32 KB

    // K1: Wt pack + cursor init
    prep_kernel<<<66, 256, 0, stream>>>(W1, W2, Wt1, Wt2, bincursor);
    // K2: bin || gemm1 (unscaled h -> HsP panels)
    bin_gemm1_kernel<<<BIN_BLOCKS + GEMM_TILES, 256, 0, stream>>>(edge_index, bincursor, pairs,
                                                                  x, Wt1, HsP);
    // K3: CSR build (chunk-sorted) + dinv
    fill2_kernel<<<NB, 256, 0, stream>>>(pairs, bincursor, rowbeg, rowend, dinv, csr_src);
    // K4: agg1 panels (dinv[src] per edge, relu -> out1P panels)
    aggP_kernel<true, true><<<AGG_TILES * NPANEL, 256, 0, stream>>>(
        rowbeg, rowend, csr_src, HsP, dinv, b1, nullptr, (void*)out1P);
    // K5: gemm2 (out1P -> HsP panels, dinv-scaled)  [reuses HsP buffer]
    gemm2_kernel<<<GEMM_TILES, 256, 0, stream>>>(out1P, Wt2, dinv, HsP);
    // K6: agg2 panels (+bias +residual, relu, fp32 out)
    aggP_kernel<false, false><<<AGG_TILES * NPANEL, 256, 0, stream>>>(
        rowbeg, rowend, csr_src, HsP, dinv, b2, x, (void*)out);
}